// Round 7
// baseline (634.464 us; speedup 1.0000x reference)
//
#include <hip/hip_runtime.h>
#include <hip/hip_bf16.h>

// Problem constants
#define BATCH 4096
#define IN_SZ 512
#define HID_SZ 2048
#define OUT_SZ 512
#define NLAYER 4
#define INNER 2560        // 512 + 2048
#define NKT (INNER / 64)  // 40 K-tiles of 64 (even -> 2x-unrolled T loop exact)

// GEMM tile: BM=128 x BN=160, BK=64; grid 32x16 = 512 blocks = 2/CU.
// 256 threads = 4 waves (2M x 2N): per-wave 64x80.
// NEW: B operand goes global->registers (wave-exclusive columns, L2-hot
// panels), LDS holds only the A-tile (2 x 16 KB). Per-CU LDS traffic drops
// from ~1728 cyc/K-tile to ~768 -> MFMA (1552 cyc) becomes critical resource.

typedef __attribute__((ext_vector_type(8))) short bf16x8;
typedef __attribute__((ext_vector_type(4))) float f32x4;

__device__ __forceinline__ unsigned short f2bf(float f) {
  unsigned int u = __float_as_uint(f);
  u += 0x7fff + ((u >> 16) & 1);  // RNE
  return (unsigned short)(u >> 16);
}

__device__ __forceinline__ void gload16(const void* g, void* l) {
  __builtin_amdgcn_global_load_lds(
      (const __attribute__((address_space(1))) unsigned int*)g,
      (__attribute__((address_space(3))) unsigned int*)l,
      16, 0, 0);
}

// ---------------- conversion kernels ----------------

// One fused fp32->bf16 conversion over all weights; dst regions contiguous:
// [Wl 26,214,400][Wio 1,310,720][Wih 5,242,880] elements.
#define NWL4  6553600   // Wl  / 4
#define NWO4  327680    // Wio / 4
#define NWH4  1310720   // Wih / 4
__global__ void cvt_all(const float* __restrict__ Wl, const float* __restrict__ Wih,
                        const float* __restrict__ Wio, unsigned short* __restrict__ dst) {
  const int n4 = NWL4 + NWO4 + NWH4;
  int i = blockIdx.x * blockDim.x + threadIdx.x;
  const int stride = gridDim.x * blockDim.x;
  for (; i < n4; i += stride) {
    const float* src;
    long off4;
    if (i < NWL4) { src = Wl; off4 = i; }
    else if (i < NWL4 + NWO4) { src = Wio; off4 = i - NWL4; }
    else { src = Wih; off4 = i - NWL4 - NWO4; }
    float4 v = *reinterpret_cast<const float4*>(src + off4 * 4);
    ushort4 o;
    o.x = f2bf(v.x); o.y = f2bf(v.y); o.z = f2bf(v.z); o.w = f2bf(v.w);
    *reinterpret_cast<ushort4*>(dst + (long)i * 4) = o;
  }
}

__global__ void build_combined(const float* __restrict__ x,
                               const float* __restrict__ h,
                               unsigned short* __restrict__ out) {
  const int n4 = BATCH * INNER / 4;
  int i = blockIdx.x * blockDim.x + threadIdx.x;
  const int stride = gridDim.x * blockDim.x;
  for (; i < n4; i += stride) {
    int row = i / (INNER / 4);
    int c4 = i - row * (INNER / 4);
    const float* src = (c4 < IN_SZ / 4) ? (x + (long)row * IN_SZ + c4 * 4)
                                        : (h + (long)row * HID_SZ + (c4 - IN_SZ / 4) * 4);
    float4 v = *reinterpret_cast<const float4*>(src);
    ushort4 o;
    o.x = f2bf(v.x); o.y = f2bf(v.y); o.z = f2bf(v.z); o.w = f2bf(v.w);
    *reinterpret_cast<ushort4*>(out + (long)i * 4) = o;
  }
}

// ---------------- 128x160 B-in-registers GEMM: C = act(A * B^T + bias) ------
// A: [4096][2560] bf16, B: [2560][2560] bf16 ('bi,oi->bo').
// LDS: 2 bufs x A 16KB = 32 KB, XOR-swizzle byte^=((row&7)<<4) (A frag reads
// would otherwise be 16-way bank conflicts).
// Per K-tile per wave: 8 ds_read_b128 (A frags), 4 gload_lds (A stage T+1),
// 10 global b128 (B frags T+1, L2-hit), 40 MFMA. One barrier + vmcnt(0)/tile
// (all VMEM issued a full tile before the wait -> drain ~free).
// B reg sets ping-pong on tile parity via 2x-unrolled loop (static indexing).

#define STAGE_A4(kt, buf) do {                                                \
  _Pragma("unroll")                                                           \
  for (int u_ = 0; u_ < 4; ++u_) {                                            \
    const int base_ = u_ * 32 + w * 8;                                        \
    gload16(A + (long)(row0 + base_ + srow) * INNER + (kt) * 64 + srcsw,      \
            (void*)(&lds[buf][base_ * 64]));                                  \
  } } while (0)

#define LOAD_AF(dst, mh, buf) do {                                           \
  const unsigned short* Ar_ = &lds[buf][0];                                  \
  _Pragma("unroll")                                                          \
  for (int m_ = 0; m_ < 2; ++m_) {                                           \
    int r_ = wr * 64 + (mh) * 32 + m_ * 16 + fr;                             \
    dst[m_][0] = *(const bf16x8*)(Ar_ + r_ * 64 + csw0);                     \
    dst[m_][1] = *(const bf16x8*)(Ar_ + r_ * 64 + csw1);                     \
  } } while (0)

// B fragments straight from global (per-lane: col = wcn*80 + n*16 + fr,
// 16 bytes at k-offset (lane>>4)*8 within the 32-wide kk slice).
#define LOAD_BG(dst, kt) do {                                                \
  _Pragma("unroll")                                                          \
  for (int n_ = 0; n_ < 5; ++n_) {                                           \
    dst[n_][0] = *(const bf16x8*)(Bbase + (long)n_ * 16 * INNER + (kt) * 64);      \
    dst[n_][1] = *(const bf16x8*)(Bbase + (long)n_ * 16 * INNER + (kt) * 64 + 32); \
  } } while (0)

#define MF_HALF(af, bq, mh) do {                                              \
  __builtin_amdgcn_s_setprio(1);                                              \
  _Pragma("unroll")                                                           \
  for (int m_ = 0; m_ < 2; ++m_)                                              \
    _Pragma("unroll")                                                         \
    for (int n_ = 0; n_ < 5; ++n_) {                                          \
      acc[(mh) * 2 + m_][n_] = __builtin_amdgcn_mfma_f32_16x16x32_bf16(       \
          af[m_][0], bq[n_][0], acc[(mh) * 2 + m_][n_], 0, 0, 0);             \
      acc[(mh) * 2 + m_][n_] = __builtin_amdgcn_mfma_f32_16x16x32_bf16(       \
          af[m_][1], bq[n_][1], acc[(mh) * 2 + m_][n_], 0, 0, 0);             \
    }                                                                         \
  __builtin_amdgcn_s_setprio(0);                                              \
} while (0)

#define SB() __builtin_amdgcn_sched_barrier(0)

// Tile body. d = tile parity (compile-time); BC = current B reg set,
// BN = next-tile B reg set (filled this tile).
#define TILE_BODY(d, BC, BN) do {                                             \
  const int T = T2 + (d);                                                     \
  const int kt1 = (T + 1 < NKT) ? T + 1 : NKT - 1; /* clamp: dup, harmless */ \
  /* issue all VMEM for T+1 first so it flies under this tile's compute */    \
  STAGE_A4(kt1, (d) ^ 1);                                                     \
  LOAD_BG(BN, kt1);                                                           \
  /* A fragment reads of tile T from buf d */                                 \
  LOAD_AF(afL, 0, d);                                                         \
  LOAD_AF(afH, 1, d);                                                         \
  SB();                                                                       \
  asm volatile("s_waitcnt lgkmcnt(4)" ::: "memory");  /* afL ready */         \
  SB();                                                                       \
  MF_HALF(afL, BC, 0);                                                        \
  asm volatile("s_waitcnt lgkmcnt(0)" ::: "memory");  /* afH ready */         \
  SB();                                                                       \
  MF_HALF(afH, BC, 1);                                                        \
  asm volatile("s_waitcnt vmcnt(0)" ::: "memory");  /* T+1 A+B landed */      \
  __builtin_amdgcn_s_barrier();                                               \
} while (0)

template <int MODE>
__global__ __launch_bounds__(256, 2)
void gemm_bg(const unsigned short* __restrict__ A, const unsigned short* __restrict__ B,
             const float* __restrict__ bias0, const float* __restrict__ bias1,
             void* __restrict__ C) {
  __shared__ unsigned short lds[2][8192];  // 32 KiB: two A-tile buffers

  const int tid = threadIdx.x;
  const int w = tid >> 6;   // 4 waves
  const int lane = tid & 63;

  // XCD mapping: 512 blocks; each XCD owns 2 adjacent 160-col B panels (1.6MB)
  const int flat = blockIdx.x;
  const int xcd = flat & 7;
  const int local = flat >> 3;           // 0..63
  const int nb = xcd * 2 + (local & 1);  // 16 N-blocks
  const int mb = local >> 1;             // 32 M-blocks
  const int row0 = mb * 128, col0 = nb * 160;
  const int wr = w >> 1, wcn = w & 1;

  // stage source swizzle (elements): inverse of LDS read swizzle
  const int srow = lane >> 3;
  const int srcsw = ((((lane & 7) << 4) ^ ((lane >> 3) << 4)) >> 1);

  // fragment read addressing
  const int fr = lane & 15;
  const int csw0 = ((((lane >> 4) << 4)) ^ ((lane & 7) << 4)) >> 1;       // kk=0
  const int csw1 = ((64 + ((lane >> 4) << 4)) ^ ((lane & 7) << 4)) >> 1;  // kk=1

  // B global base for this lane: col = col0 + wcn*80 + fr, k-offset (lane>>4)*8
  const unsigned short* Bbase =
      B + (long)(col0 + wcn * 80 + fr) * INNER + ((lane >> 4) * 8);

  f32x4 acc[4][5] = {};
  bf16x8 afL[2][2], afH[2][2];
  bf16x8 bq0[5][2], bq1[5][2];

  // prologue: A(0)->buf0, B(0)->bq0
  STAGE_A4(0, 0);
  LOAD_BG(bq0, 0);
  asm volatile("s_waitcnt vmcnt(0)" ::: "memory");
  __builtin_amdgcn_s_barrier();
  SB();

  for (int T2 = 0; T2 < NKT; T2 += 2) {
    TILE_BODY(0, bq0, bq1);
    TILE_BODY(1, bq1, bq0);
  }

  // epilogue: C/D layout col = lane&15, row = (lane>>4)*4 + j
  const int erow = row0 + wr * 64 + ((lane >> 4) << 2);
  const int ecol = col0 + wcn * 80 + fr;
  if (MODE == 0) {
    unsigned short* Co = (unsigned short*)C;
#pragma unroll
    for (int n = 0; n < 5; ++n) {
      const int col = ecol + n * 16;
      const float bv = bias0[col];
#pragma unroll
      for (int m = 0; m < 4; ++m) {
        const int row = erow + m * 16;
#pragma unroll
        for (int j = 0; j < 4; ++j) {
          float v = acc[m][n][j] + bv;
          v = fmaxf(v, 0.0f);
          Co[(long)(row + j) * INNER + col] = f2bf(v);
        }
      }
    }
  } else {
    float* outO = (float*)C;                          // [4096,512]
    float* outH = (float*)C + (long)BATCH * OUT_SZ;   // [4096,2048]
#pragma unroll
    for (int n = 0; n < 5; ++n) {
      const int col = ecol + n * 16;
      if (col < OUT_SZ) {
        const float bv = bias0[col];
#pragma unroll
        for (int m = 0; m < 4; ++m) {
          const int row = erow + m * 16;
#pragma unroll
          for (int j = 0; j < 4; ++j)
            outO[(long)(row + j) * OUT_SZ + col] = acc[m][n][j] + bv;
        }
      } else {
        const int hc = col - OUT_SZ;
        const float bv = bias1[hc];
#pragma unroll
        for (int m = 0; m < 4; ++m) {
          const int row = erow + m * 16;
#pragma unroll
          for (int j = 0; j < 4; ++j)
            outH[(long)(row + j) * HID_SZ + hc] = tanhf(acc[m][n][j] + bv);
        }
      }
    }
  }
}

// ---------------- launcher ----------------

extern "C" void kernel_launch(void* const* d_in, const int* in_sizes, int n_in,
                              void* d_out, int out_size, void* d_ws, size_t ws_size,
                              hipStream_t stream) {
  const float* x   = (const float*)d_in[0];
  const float* h   = (const float*)d_in[1];
  const float* Wl  = (const float*)d_in[2];  // [4,2560,2560]
  const float* bl  = (const float*)d_in[3];  // [4,2560]
  const float* Wih = (const float*)d_in[4];  // [2048,2560]
  const float* bih = (const float*)d_in[5];  // [2048]
  const float* Wio = (const float*)d_in[6];  // [512,2560]
  const float* bio = (const float*)d_in[7];  // [512]

  unsigned short* ws   = (unsigned short*)d_ws;
  unsigned short* Wlb  = ws;                                   // 4*2560*2560
  unsigned short* Whb  = Wlb + (long)NLAYER * INNER * INNER;   // fused heads [2560][2560]
  unsigned short* act0 = Whb + (long)INNER * INNER;
  unsigned short* act1 = act0 + (long)BATCH * INNER;

  // fp32 -> bf16 weight conversion (single fused kernel; dst contiguous:
  // Wl then Wio then Wih == Wlb ++ Whb layout)
  cvt_all<<<2048, 256, 0, stream>>>(Wl, Wih, Wio, Wlb);
  build_combined<<<2048, 256, 0, stream>>>(x, h, act0);

  // 4 square layers, ping-pong
  unsigned short* a_in = act0;
  unsigned short* a_out = act1;
  for (int l = 0; l < NLAYER; ++l) {
    gemm_bg<0><<<512, 256, 0, stream>>>(a_in, Wlb + (long)l * INNER * INNER,
                                        bl + (long)l * INNER, nullptr, a_out);
    unsigned short* t = a_in; a_in = a_out; a_out = t;
  }

  // fused heads: output (cols 0-511) + tanh hidden (cols 512-2559)
  gemm_bg<1><<<512, 256, 0, stream>>>(a_in, Whb, bio, bih, d_out);
}

// Round 8
// 322.374 us; speedup vs baseline: 1.9681x; 1.9681x over previous
//
#include <hip/hip_runtime.h>
#include <hip/hip_bf16.h>

// Problem constants
#define BATCH 4096
#define IN_SZ 512
#define HID_SZ 2048
#define OUT_SZ 512
#define NLAYER 4
#define INNER 2560        // 512 + 2048
#define NKT (INNER / 64)  // 40 K-tiles of 64

// GEMM tile: BM=128 x BN=160, BK=64; grid 32x16 = 512 blocks = 2/CU.
// 128 threads = 2 waves, each wave computes 128x80 (8 m-frags x 5 n-frags).
// Per K-tile per CU: LDS reads 104 x b128 (1248 cyc) < MFMA 320 x 4.85 (1552)
// -> MFMA-bound (R6's 64x80 wave-tile was LDS-fabric-bound at 1728 cyc).
// B stays in LDS (R7 proved global B-fragments are uncoalesced 64-line gathers).

typedef __attribute__((ext_vector_type(8))) short bf16x8;
typedef __attribute__((ext_vector_type(4))) float f32x4;

__device__ __forceinline__ unsigned short f2bf(float f) {
  unsigned int u = __float_as_uint(f);
  u += 0x7fff + ((u >> 16) & 1);  // RNE
  return (unsigned short)(u >> 16);
}

__device__ __forceinline__ void gload16(const void* g, void* l) {
  __builtin_amdgcn_global_load_lds(
      (const __attribute__((address_space(1))) unsigned int*)g,
      (__attribute__((address_space(3))) unsigned int*)l,
      16, 0, 0);
}

// ---------------- conversion kernels ----------------

#define NWL4  6553600   // Wl  / 4
#define NWO4  327680    // Wio / 4
#define NWH4  1310720   // Wih / 4
__global__ void cvt_all(const float* __restrict__ Wl, const float* __restrict__ Wih,
                        const float* __restrict__ Wio, unsigned short* __restrict__ dst) {
  const int n4 = NWL4 + NWO4 + NWH4;
  int i = blockIdx.x * blockDim.x + threadIdx.x;
  const int stride = gridDim.x * blockDim.x;
  for (; i < n4; i += stride) {
    const float* src;
    long off4;
    if (i < NWL4) { src = Wl; off4 = i; }
    else if (i < NWL4 + NWO4) { src = Wio; off4 = i - NWL4; }
    else { src = Wih; off4 = i - NWL4 - NWO4; }
    float4 v = *reinterpret_cast<const float4*>(src + off4 * 4);
    ushort4 o;
    o.x = f2bf(v.x); o.y = f2bf(v.y); o.z = f2bf(v.z); o.w = f2bf(v.w);
    *reinterpret_cast<ushort4*>(dst + (long)i * 4) = o;
  }
}

__global__ void build_combined(const float* __restrict__ x,
                               const float* __restrict__ h,
                               unsigned short* __restrict__ out) {
  const int n4 = BATCH * INNER / 4;
  int i = blockIdx.x * blockDim.x + threadIdx.x;
  const int stride = gridDim.x * blockDim.x;
  for (; i < n4; i += stride) {
    int row = i / (INNER / 4);
    int c4 = i - row * (INNER / 4);
    const float* src = (c4 < IN_SZ / 4) ? (x + (long)row * IN_SZ + c4 * 4)
                                        : (h + (long)row * HID_SZ + (c4 - IN_SZ / 4) * 4);
    float4 v = *reinterpret_cast<const float4*>(src);
    ushort4 o;
    o.x = f2bf(v.x); o.y = f2bf(v.y); o.z = f2bf(v.z); o.w = f2bf(v.w);
    *reinterpret_cast<ushort4*>(out + (long)i * 4) = o;
  }
}

// ---------------- 128x160 big-wave-tile GEMM: C = act(A * B^T + bias) -------
// A: [4096][2560] bf16, B: [2560][2560] bf16 ('bi,oi->bo').
// LDS: 2 bufs x (A 16KB [0,8192) + B 20KB [8192,18432)) = 72 KB,
// XOR-swizzle byte^=((row&7)<<4).
// Staging: 18 units/K-tile (A u0-7, B v0-9; 16 rows each; 1 gload16/thread,
// wave w covers rows w*8..w*8+7 of each unit). Rotation during tile T (buf d):
//   P0: T+1 {v5..v9} -> d^1   P1: T+1 {u0..u4} -> d^1
//   P2: T+2 {v0..v4} -> d     P3: T+2 {u5..u7} -> d; vmcnt(8) validates T+1
// (T+1's {v0-4,u5-7} staged during T-1's P2/P3.)
// Fragment groups (20 MFMA each), reads issued one phase ahead, counted lgkm:
//   P3_prev: afA(mh0,kk0)+bqA(kk0) [9] -> lgkm(9)@P0 -> MF(afA,bqA,mh0)
//   P0: afB(mh0,kk1)+bqB(kk1) [9]      -> lgkm(4)@P1 -> MF(afB,bqB,mh0)
//   P1: afC(mh1,kk0) [4]               -> lgkm(4)@P2 -> MF(afC,bqA,mh1)
//   P2: afD(mh1,kk1) [4]               -> lgkm(9)@P3 -> MF(afD,bqB,mh1)
// Overwrite-vs-read safety: all B reads of buf d retired by P1-mid (P2 B-stage
// safe); A mh1 reads retired by P3-mid, staged regions' reads >=1 full phase
// older than the overwriting gload's return (ds pipe completes once issued).

#define STAGE_A(kt, u, buf) do {                                              \
  const int base_ = (u) * 16 + w * 8;                                         \
  gload16(A + (long)(row0 + base_ + srow) * INNER + (kt) * 64 + srcsw,        \
          (void*)(&lds[buf][base_ * 64]));                                    \
} while (0)

#define STAGE_B(kt, v, buf) do {                                              \
  const int base_ = (v) * 16 + w * 8;                                         \
  gload16(B + (long)(col0 + base_ + srow) * INNER + (kt) * 64 + srcsw,        \
          (void*)(&lds[buf][8192 + base_ * 64]));                             \
} while (0)

#define LOAD_AFK(dst, mh, CSW, buf) do {                                      \
  const unsigned short* Ar_ = &lds[buf][0];                                   \
  _Pragma("unroll")                                                           \
  for (int m_ = 0; m_ < 4; ++m_)                                              \
    dst[m_] = *(const bf16x8*)(Ar_ + ((mh) * 64 + m_ * 16 + fr) * 64 + (CSW)); \
} while (0)

#define LOAD_BQK(dst, CSW, buf) do {                                          \
  const unsigned short* Br_ = &lds[buf][8192];                                \
  _Pragma("unroll")                                                           \
  for (int n_ = 0; n_ < 5; ++n_)                                              \
    dst[n_] = *(const bf16x8*)(Br_ + (w * 80 + n_ * 16 + fr) * 64 + (CSW));   \
} while (0)

#define MF(af, bq, mh) do {                                                   \
  __builtin_amdgcn_s_setprio(1);                                              \
  _Pragma("unroll")                                                           \
  for (int m_ = 0; m_ < 4; ++m_)                                              \
    _Pragma("unroll")                                                         \
    for (int n_ = 0; n_ < 5; ++n_)                                            \
      acc[(mh) * 4 + m_][n_] = __builtin_amdgcn_mfma_f32_16x16x32_bf16(       \
          af[m_], bq[n_], acc[(mh) * 4 + m_][n_], 0, 0, 0);                   \
  __builtin_amdgcn_s_setprio(0);                                              \
} while (0)

#define SB() __builtin_amdgcn_sched_barrier(0)

template <int MODE>
__global__ __launch_bounds__(128, 1)
void gemm_bw(const unsigned short* __restrict__ A, const unsigned short* __restrict__ B,
             const float* __restrict__ bias0, const float* __restrict__ bias1,
             void* __restrict__ C) {
  __shared__ unsigned short lds[2][18432];  // 72 KiB

  const int tid = threadIdx.x;
  const int w = tid >> 6;   // 2 waves
  const int lane = tid & 63;

  // XCD mapping: 512 blocks; each XCD owns 2 adjacent 160-col B panels
  const int flat = blockIdx.x;
  const int xcd = flat & 7;
  const int local = flat >> 3;           // 0..63
  const int nb = xcd * 2 + (local & 1);  // 16 N-blocks
  const int mb = local >> 1;             // 32 M-blocks
  const int row0 = mb * 128, col0 = nb * 160;

  // stage source swizzle (elements): inverse of LDS read swizzle
  const int srow = lane >> 3;
  const int srcsw = ((((lane & 7) << 4) ^ ((lane >> 3) << 4)) >> 1);

  // fragment read addressing
  const int fr = lane & 15;
  const int csw0 = ((((lane >> 4) << 4)) ^ ((lane & 7) << 4)) >> 1;       // kk=0
  const int csw1 = ((64 + ((lane >> 4) << 4)) ^ ((lane & 7) << 4)) >> 1;  // kk=1

  f32x4 acc[8][5] = {};
  bf16x8 afA[4], afB[4], afC[4], afD[4];
  bf16x8 bqA[5], bqB[5];

  // prologue: tile0 all 18 units -> buf0; tile1 {v0-4, u5-7} -> buf1
  STAGE_A(0, 0, 0); STAGE_A(0, 1, 0); STAGE_A(0, 2, 0); STAGE_A(0, 3, 0);
  STAGE_A(0, 4, 0); STAGE_A(0, 5, 0); STAGE_A(0, 6, 0); STAGE_A(0, 7, 0);
  STAGE_B(0, 0, 0); STAGE_B(0, 1, 0); STAGE_B(0, 2, 0); STAGE_B(0, 3, 0);
  STAGE_B(0, 4, 0); STAGE_B(0, 5, 0); STAGE_B(0, 6, 0); STAGE_B(0, 7, 0);
  STAGE_B(0, 8, 0); STAGE_B(0, 9, 0);
  STAGE_B(1, 0, 1); STAGE_B(1, 1, 1); STAGE_B(1, 2, 1); STAGE_B(1, 3, 1);
  STAGE_B(1, 4, 1);
  STAGE_A(1, 5, 1); STAGE_A(1, 6, 1); STAGE_A(1, 7, 1);
  asm volatile("s_waitcnt vmcnt(8)" ::: "memory");  // tile0 landed
  __builtin_amdgcn_s_barrier();
  SB();
  LOAD_AFK(afA, 0, csw0, 0);
  LOAD_BQK(bqA, csw0, 0);
  SB();

  for (int T = 0; T < NKT; ++T) {
    const int d = T & 1;
    const int kt1 = (T + 1 < NKT) ? T + 1 : NKT - 1;  // clamp: dup-stage same bytes, benign
    const int kt2 = (T + 2 < NKT) ? T + 2 : NKT - 1;

    // P0: reads afB,bqB (kk1) [9]; stage T+1 {v5-9} -> d^1; MF(afA,bqA,mh0)
    LOAD_AFK(afB, 0, csw1, d);
    LOAD_BQK(bqB, csw1, d);
    STAGE_B(kt1, 5, d ^ 1); STAGE_B(kt1, 6, d ^ 1); STAGE_B(kt1, 7, d ^ 1);
    STAGE_B(kt1, 8, d ^ 1); STAGE_B(kt1, 9, d ^ 1);
    SB();
    asm volatile("s_waitcnt lgkmcnt(9)" ::: "memory");  // afA,bqA ready
    SB();
    MF(afA, bqA, 0);
    __builtin_amdgcn_s_barrier();

    // P1: reads afC (mh1,kk0) [4]; stage T+1 {u0-4} -> d^1; MF(afB,bqB,mh0)
    LOAD_AFK(afC, 1, csw0, d);
    STAGE_A(kt1, 0, d ^ 1); STAGE_A(kt1, 1, d ^ 1); STAGE_A(kt1, 2, d ^ 1);
    STAGE_A(kt1, 3, d ^ 1); STAGE_A(kt1, 4, d ^ 1);
    SB();
    asm volatile("s_waitcnt lgkmcnt(4)" ::: "memory");  // afB,bqB ready
    SB();
    MF(afB, bqB, 0);
    __builtin_amdgcn_s_barrier();

    // P2: reads afD (mh1,kk1) [4]; stage T+2 {v0-4} -> d; MF(afC,bqA,mh1)
    LOAD_AFK(afD, 1, csw1, d);
    STAGE_B(kt2, 0, d); STAGE_B(kt2, 1, d); STAGE_B(kt2, 2, d);
    STAGE_B(kt2, 3, d); STAGE_B(kt2, 4, d);
    SB();
    asm volatile("s_waitcnt lgkmcnt(4)" ::: "memory");  // afC ready
    SB();
    MF(afC, bqA, 1);
    __builtin_amdgcn_s_barrier();

    // P3: stage T+2 {u5-7} -> d; vmcnt(8) validates T+1; barrier;
    //     read next-tile afA,bqA from d^1; MF(afD,bqB,mh1)
    STAGE_A(kt2, 5, d); STAGE_A(kt2, 6, d); STAGE_A(kt2, 7, d);
    asm volatile("s_waitcnt vmcnt(8)" ::: "memory");  // T+1 fully landed
    __builtin_amdgcn_s_barrier();
    SB();
    LOAD_AFK(afA, 0, csw0, d ^ 1);
    LOAD_BQK(bqA, csw0, d ^ 1);
    SB();
    asm volatile("s_waitcnt lgkmcnt(9)" ::: "memory");  // afD ready
    SB();
    MF(afD, bqB, 1);
    __builtin_amdgcn_s_barrier();
  }
  asm volatile("s_waitcnt vmcnt(0)" ::: "memory");  // drain gloads before endpgm

  // epilogue: C/D layout col = lane&15, row = (lane>>4)*4 + j
  const int erow = row0 + ((lane >> 4) << 2);
  const int ecol = col0 + w * 80 + fr;
  if (MODE == 0) {
    unsigned short* Co = (unsigned short*)C;
#pragma unroll
    for (int n = 0; n < 5; ++n) {
      const int col = ecol + n * 16;
      const float bv = bias0[col];
#pragma unroll
      for (int mh = 0; mh < 2; ++mh)
#pragma unroll
        for (int m_ = 0; m_ < 4; ++m_) {
          const int row = erow + mh * 64 + m_ * 16;
#pragma unroll
          for (int j = 0; j < 4; ++j) {
            float v = acc[mh * 4 + m_][n][j] + bv;
            v = fmaxf(v, 0.0f);
            Co[(long)(row + j) * INNER + col] = f2bf(v);
          }
        }
    }
  } else {
    float* outO = (float*)C;                          // [4096,512]
    float* outH = (float*)C + (long)BATCH * OUT_SZ;   // [4096,2048]
#pragma unroll
    for (int n = 0; n < 5; ++n) {
      const int col = ecol + n * 16;
      if (col < OUT_SZ) {
        const float bv = bias0[col];
#pragma unroll
        for (int mh = 0; mh < 2; ++mh)
#pragma unroll
          for (int m_ = 0; m_ < 4; ++m_) {
            const int row = erow + mh * 64 + m_ * 16;
#pragma unroll
            for (int j = 0; j < 4; ++j)
              outO[(long)(row + j) * OUT_SZ + col] = acc[mh * 4 + m_][n][j] + bv;
          }
      } else {
        const int hc = col - OUT_SZ;
        const float bv = bias1[hc];
#pragma unroll
        for (int mh = 0; mh < 2; ++mh)
#pragma unroll
          for (int m_ = 0; m_ < 4; ++m_) {
            const int row = erow + mh * 64 + m_ * 16;
#pragma unroll
            for (int j = 0; j < 4; ++j)
              outH[(long)(row + j) * HID_SZ + hc] = tanhf(acc[mh * 4 + m_][n][j] + bv);
          }
      }
    }
  }
}

// ---------------- launcher ----------------

extern "C" void kernel_launch(void* const* d_in, const int* in_sizes, int n_in,
                              void* d_out, int out_size, void* d_ws, size_t ws_size,
                              hipStream_t stream) {
  const float* x   = (const float*)d_in[0];
  const float* h   = (const float*)d_in[1];
  const float* Wl  = (const float*)d_in[2];  // [4,2560,2560]
  const float* bl  = (const float*)d_in[3];  // [4,2560]
  const float* Wih = (const float*)d_in[4];  // [2048,2560]
  const float* bih = (const float*)d_in[5];  // [2048]
  const float* Wio = (const float*)d_in[6];  // [512,2560]
  const float* bio = (const float*)d_in[7];  // [512]

  unsigned short* ws   = (unsigned short*)d_ws;
  unsigned short* Wlb  = ws;                                   // 4*2560*2560
  unsigned short* Whb  = Wlb + (long)NLAYER * INNER * INNER;   // fused heads [2560][2560]
  unsigned short* act0 = Whb + (long)INNER * INNER;
  unsigned short* act1 = act0 + (long)BATCH * INNER;

  // fp32 -> bf16 weight conversion (dst contiguous: Wl ++ Wio ++ Wih)
  cvt_all<<<2048, 256, 0, stream>>>(Wl, Wih, Wio, Wlb);
  build_combined<<<2048, 256, 0, stream>>>(x, h, act0);

  // 4 square layers, ping-pong
  unsigned short* a_in = act0;
  unsigned short* a_out = act1;
  for (int l = 0; l < NLAYER; ++l) {
    gemm_bw<0><<<512, 128, 0, stream>>>(a_in, Wlb + (long)l * INNER * INNER,
                                        bl + (long)l * INNER, nullptr, a_out);
    unsigned short* t = a_in; a_in = a_out; a_out = t;
  }

  // fused heads: output (cols 0-511) + tanh hidden (cols 512-2559)
  gemm_bw<1><<<512, 128, 0, stream>>>(a_in, Whb, bio, bih, d_out);
}

// Round 9
// 300.548 us; speedup vs baseline: 2.1110x; 1.0726x over previous
//
#include <hip/hip_runtime.h>
#include <hip/hip_bf16.h>

// Problem constants
#define BATCH 4096
#define IN_SZ 512
#define HID_SZ 2048
#define OUT_SZ 512
#define NLAYER 4
#define INNER 2560        // 512 + 2048
#define NKT (INNER / 64)  // 40 K-tiles of 64

// GEMM tile: BM=128 x BN=160, BK=64; grid 32x16 = 512 blocks = 2/CU.
// 256 threads = 4 waves (2M x 2N), per-wave 64x80 (forced geometry: 2048
// wave-tiles = 8 waves/CU = 2/SIMD; R8 proved 1 wave/SIMD collapses).
// THIS ROUND vs R6: barriers per K-tile cut 8 -> 3. Only hazard-required
// syncs remain: P1-end (protects P2's B-restage into live buf), P2-end
// (protects P3's A-restage), P3's vmcnt(4)+barrier (validates tile T+1
// before its fragment loads). All other waits are per-wave counted lgkmcnt.

typedef __attribute__((ext_vector_type(8))) short bf16x8;
typedef __attribute__((ext_vector_type(4))) float f32x4;

__device__ __forceinline__ unsigned short f2bf(float f) {
  unsigned int u = __float_as_uint(f);
  u += 0x7fff + ((u >> 16) & 1);  // RNE
  return (unsigned short)(u >> 16);
}

__device__ __forceinline__ void gload16(const void* g, void* l) {
  __builtin_amdgcn_global_load_lds(
      (const __attribute__((address_space(1))) unsigned int*)g,
      (__attribute__((address_space(3))) unsigned int*)l,
      16, 0, 0);
}

// ---------------- conversion kernels ----------------

#define NWL4  6553600   // Wl  / 4
#define NWO4  327680    // Wio / 4
#define NWH4  1310720   // Wih / 4
__global__ void cvt_all(const float* __restrict__ Wl, const float* __restrict__ Wih,
                        const float* __restrict__ Wio, unsigned short* __restrict__ dst) {
  const int n4 = NWL4 + NWO4 + NWH4;
  int i = blockIdx.x * blockDim.x + threadIdx.x;
  const int stride = gridDim.x * blockDim.x;
  for (; i < n4; i += stride) {
    const float* src;
    long off4;
    if (i < NWL4) { src = Wl; off4 = i; }
    else if (i < NWL4 + NWO4) { src = Wio; off4 = i - NWL4; }
    else { src = Wih; off4 = i - NWL4 - NWO4; }
    float4 v = *reinterpret_cast<const float4*>(src + off4 * 4);
    ushort4 o;
    o.x = f2bf(v.x); o.y = f2bf(v.y); o.z = f2bf(v.z); o.w = f2bf(v.w);
    *reinterpret_cast<ushort4*>(dst + (long)i * 4) = o;
  }
}

__global__ void build_combined(const float* __restrict__ x,
                               const float* __restrict__ h,
                               unsigned short* __restrict__ out) {
  const int n4 = BATCH * INNER / 4;
  int i = blockIdx.x * blockDim.x + threadIdx.x;
  const int stride = gridDim.x * blockDim.x;
  for (; i < n4; i += stride) {
    int row = i / (INNER / 4);
    int c4 = i - row * (INNER / 4);
    const float* src = (c4 < IN_SZ / 4) ? (x + (long)row * IN_SZ + c4 * 4)
                                        : (h + (long)row * HID_SZ + (c4 - IN_SZ / 4) * 4);
    float4 v = *reinterpret_cast<const float4*>(src);
    ushort4 o;
    o.x = f2bf(v.x); o.y = f2bf(v.y); o.z = f2bf(v.z); o.w = f2bf(v.w);
    *reinterpret_cast<ushort4*>(out + (long)i * 4) = o;
  }
}

// ---------------- 128x160 3-barrier GEMM: C = act(A * B^T + bias) -----------
// A: [4096][2560] bf16, B: [2560][2560] bf16 ('bi,oi->bo').
// LDS: 2 bufs x (A 16KB [0,8192) + B 20KB [8192,18432)) = 72 KB,
// XOR-swizzle byte^=((row&7)<<4).
// Staging: 9 units/K-tile (A u0-3 = 32 rows each; B u4-8 = 32 rows each),
// 1 gload16/thread per unit. Rotation during tile T (reading buf d):
//   P0: T+1 {u6,u7,u8} -> d^1   P1: T+1 {u0,u1} -> d^1
//   P2: T+2 {u4,u5} -> d        P3: T+2 {u2,u3} -> d; vmcnt(4) validates T+1
// Fragment reads one phase ahead, counted lgkm (per-wave, no barrier):
//   prev P3: afA,bqA of T [10] -> lgkm(4)@P0   P0: bqB [4] -> lgkm(4)@P1
//   P1: afB [4] -> lgkm(0)@P2                  P3: next-tile afA,bqA
// Hazard-required barriers only:
//   P1-end: all waves' B reads (bqA@P0-lgkm, bqB@P1-lgkm) retired before
//           P2's stage of B rows 0-63 into live buf d.
//   P2-end: all waves' A-mh1 reads (afB@P2-lgkm) retired before P3's stage
//           of A rows 64-127 into live buf d.
//   P3 vmcnt(4)+barrier: tile T+1's 9 units (T-1:P2,P3 + T:P0,P1) all
//           retired in every wave before the T+1 fragment loads.

#define STAGE_U(kt, u, buf) do {                                              \
  if ((u) < 4) {                                                              \
    const int base_ = (u) * 32 + w * 8;                                       \
    gload16(A + (long)(row0 + base_ + srow) * INNER + (kt) * 64 + srcsw,      \
            (void*)(&lds[buf][base_ * 64]));                                  \
  } else {                                                                    \
    const int base_ = ((u) - 4) * 32 + w * 8;                                 \
    gload16(B + (long)(col0 + base_ + srow) * INNER + (kt) * 64 + srcsw,      \
            (void*)(&lds[buf][8192 + base_ * 64]));                           \
  } } while (0)

#define LOAD_AF(dst, mh, buf) do {                                           \
  const unsigned short* Ar_ = &lds[buf][0];                                  \
  _Pragma("unroll")                                                          \
  for (int m_ = 0; m_ < 2; ++m_) {                                           \
    int r_ = wr * 64 + (mh) * 32 + m_ * 16 + fr;                             \
    dst[m_][0] = *(const bf16x8*)(Ar_ + r_ * 64 + csw0);                     \
    dst[m_][1] = *(const bf16x8*)(Ar_ + r_ * 64 + csw1);                     \
  } } while (0)

#define LOAD_BQA(dst, buf) do {                                              \
  const unsigned short* Br_ = &lds[buf][8192];                               \
  _Pragma("unroll")                                                          \
  for (int n_ = 0; n_ < 3; ++n_) {                                           \
    int r_ = wcn * 80 + n_ * 16 + fr;                                        \
    dst[n_][0] = *(const bf16x8*)(Br_ + r_ * 64 + csw0);                     \
    dst[n_][1] = *(const bf16x8*)(Br_ + r_ * 64 + csw1);                     \
  } } while (0)

#define LOAD_BQB(dst, buf) do {                                              \
  const unsigned short* Br_ = &lds[buf][8192];                               \
  _Pragma("unroll")                                                          \
  for (int n_ = 0; n_ < 2; ++n_) {                                           \
    int r_ = wcn * 80 + (3 + n_) * 16 + fr;                                  \
    dst[n_][0] = *(const bf16x8*)(Br_ + r_ * 64 + csw0);                     \
    dst[n_][1] = *(const bf16x8*)(Br_ + r_ * 64 + csw1);                     \
  } } while (0)

#define MF_A(af, bq, mh) do {                                                 \
  __builtin_amdgcn_s_setprio(1);                                              \
  _Pragma("unroll")                                                           \
  for (int m_ = 0; m_ < 2; ++m_)                                              \
    _Pragma("unroll")                                                         \
    for (int n_ = 0; n_ < 3; ++n_) {                                          \
      acc[(mh) * 2 + m_][n_] = __builtin_amdgcn_mfma_f32_16x16x32_bf16(       \
          af[m_][0], bq[n_][0], acc[(mh) * 2 + m_][n_], 0, 0, 0);             \
      acc[(mh) * 2 + m_][n_] = __builtin_amdgcn_mfma_f32_16x16x32_bf16(       \
          af[m_][1], bq[n_][1], acc[(mh) * 2 + m_][n_], 0, 0, 0);             \
    }                                                                         \
  __builtin_amdgcn_s_setprio(0);                                              \
} while (0)

#define MF_B(af, bq, mh) do {                                                 \
  __builtin_amdgcn_s_setprio(1);                                              \
  _Pragma("unroll")                                                           \
  for (int m_ = 0; m_ < 2; ++m_)                                              \
    _Pragma("unroll")                                                         \
    for (int n_ = 0; n_ < 2; ++n_) {                                          \
      acc[(mh) * 2 + m_][3 + n_] = __builtin_amdgcn_mfma_f32_16x16x32_bf16(   \
          af[m_][0], bq[n_][0], acc[(mh) * 2 + m_][3 + n_], 0, 0, 0);         \
      acc[(mh) * 2 + m_][3 + n_] = __builtin_amdgcn_mfma_f32_16x16x32_bf16(   \
          af[m_][1], bq[n_][1], acc[(mh) * 2 + m_][3 + n_], 0, 0, 0);         \
    }                                                                         \
  __builtin_amdgcn_s_setprio(0);                                              \
} while (0)

#define SB() __builtin_amdgcn_sched_barrier(0)

// Tile body. d = tile parity (compile-time), AC/QC = current afA/bqA sets,
// AN/QN = next-tile sets (loaded at P3 after the validation barrier).
#define TILE_BODY(d, AC, QC, AN, QN) do {                                     \
  const int T = T2 + (d);                                                     \
  const int kt1 = (T + 1 < NKT) ? T + 1 : NKT - 1;  /* clamp: dup, benign */  \
  const int kt2 = (T + 2 < NKT) ? T + 2 : NKT - 1;                            \
  /* P0: issue bqB(T); stage T+1 {u6,u7,u8} -> d^1; MFMA Q0 = AC x QC */      \
  LOAD_BQB(bqB, d);                                                           \
  STAGE_U(kt1, 6, (d) ^ 1); STAGE_U(kt1, 7, (d) ^ 1); STAGE_U(kt1, 8, (d) ^ 1); \
  SB();                                                                       \
  asm volatile("s_waitcnt lgkmcnt(4)" ::: "memory");  /* AC,QC done */        \
  SB();                                                                       \
  MF_A(AC, QC, 0);                                                            \
  /* P1: issue afB(T); stage T+1 {u0,u1} -> d^1; MFMA Q1 = AC x bqB */        \
  LOAD_AF(afB, 1, d);                                                         \
  STAGE_U(kt1, 0, (d) ^ 1); STAGE_U(kt1, 1, (d) ^ 1);                         \
  SB();                                                                       \
  asm volatile("s_waitcnt lgkmcnt(4)" ::: "memory");  /* bqB done */          \
  SB();                                                                       \
  MF_B(AC, bqB, 0);                                                           \
  __builtin_amdgcn_s_barrier();  /* P1e: B reads of buf d retired (all waves) */ \
  /* P2: stage T+2 {u4,u5} -> d (B rows 0-63); MFMA Q2 = afB x bqB */         \
  STAGE_U(kt2, 4, d); STAGE_U(kt2, 5, d);                                     \
  SB();                                                                       \
  asm volatile("s_waitcnt lgkmcnt(0)" ::: "memory");  /* afB done */          \
  SB();                                                                       \
  MF_B(afB, bqB, 1);                                                          \
  __builtin_amdgcn_s_barrier();  /* P2e: A-mh1 reads retired (all waves) */   \
  /* P3: stage T+2 {u2,u3} -> d (A rows 64-127); validate T+1; MFMA Q3 */     \
  STAGE_U(kt2, 2, d); STAGE_U(kt2, 3, d);                                     \
  asm volatile("s_waitcnt vmcnt(4)" ::: "memory");  /* T+1 fully landed */    \
  __builtin_amdgcn_s_barrier();  /* P3b: T+1 visible to all waves */          \
  SB();                                                                       \
  LOAD_AF(AN, 0, (d) ^ 1);                                                    \
  LOAD_BQA(QN, (d) ^ 1);                                                      \
  SB();  /* pin read-issue before the MFMA cluster */                         \
  MF_A(afB, QC, 1);                                                           \
} while (0)

template <int MODE>
__global__ __launch_bounds__(256, 2)
void gemm8(const unsigned short* __restrict__ A, const unsigned short* __restrict__ B,
           const float* __restrict__ bias0, const float* __restrict__ bias1,
           void* __restrict__ C) {
  __shared__ unsigned short lds[2][18432];  // 72 KiB: A [0,8192), B [8192,18432)

  const int tid = threadIdx.x;
  const int w = tid >> 6;   // 4 waves
  const int lane = tid & 63;

  // XCD mapping: 512 blocks; each XCD owns 2 adjacent 160-col B panels
  const int flat = blockIdx.x;
  const int xcd = flat & 7;
  const int local = flat >> 3;           // 0..63
  const int nb = xcd * 2 + (local & 1);  // 16 N-blocks
  const int mb = local >> 1;             // 32 M-blocks
  const int row0 = mb * 128, col0 = nb * 160;
  const int wr = w >> 1, wcn = w & 1;

  // stage source swizzle (elements): inverse of LDS read swizzle
  const int srow = lane >> 3;
  const int srcsw = ((((lane & 7) << 4) ^ ((lane >> 3) << 4)) >> 1);

  // fragment read addressing
  const int fr = lane & 15;
  const int csw0 = ((((lane >> 4) << 4)) ^ ((lane & 7) << 4)) >> 1;       // kk=0
  const int csw1 = ((64 + ((lane >> 4) << 4)) ^ ((lane & 7) << 4)) >> 1;  // kk=1

  f32x4 acc[4][5] = {};
  bf16x8 afA0[2][2], afA1[2][2], afB[2][2];
  bf16x8 bqA0[3][2], bqA1[3][2], bqB[2][2];

  // prologue: tile 0 fully (9 units) + tile 1's {u4,u5,u2,u3}; frag reads
  STAGE_U(0, 0, 0); STAGE_U(0, 1, 0); STAGE_U(0, 2, 0); STAGE_U(0, 3, 0);
  STAGE_U(0, 4, 0); STAGE_U(0, 5, 0); STAGE_U(0, 6, 0); STAGE_U(0, 7, 0);
  STAGE_U(0, 8, 0);
  STAGE_U(1, 4, 1); STAGE_U(1, 5, 1); STAGE_U(1, 2, 1); STAGE_U(1, 3, 1);
  asm volatile("s_waitcnt vmcnt(4)" ::: "memory");  // tile 0 landed
  __builtin_amdgcn_s_barrier();
  SB();
  LOAD_AF(afA0, 0, 0);
  LOAD_BQA(bqA0, 0);
  SB();

  for (int T2 = 0; T2 < NKT; T2 += 2) {
    TILE_BODY(0, afA0, bqA0, afA1, bqA1);
    TILE_BODY(1, afA1, bqA1, afA0, bqA0);
  }
  asm volatile("s_waitcnt vmcnt(0)" ::: "memory");

  // epilogue: C/D layout col = lane&15, row = (lane>>4)*4 + j
  const int erow = row0 + wr * 64 + ((lane >> 4) << 2);
  const int ecol = col0 + wcn * 80 + fr;
  if (MODE == 0) {
    unsigned short* Co = (unsigned short*)C;
#pragma unroll
    for (int n = 0; n < 5; ++n) {
      const int col = ecol + n * 16;
      const float bv = bias0[col];
#pragma unroll
      for (int m = 0; m < 4; ++m) {
        const int row = erow + m * 16;
#pragma unroll
        for (int j = 0; j < 4; ++j) {
          float v = acc[m][n][j] + bv;
          v = fmaxf(v, 0.0f);
          Co[(long)(row + j) * INNER + col] = f2bf(v);
        }
      }
    }
  } else {
    float* outO = (float*)C;                          // [4096,512]
    float* outH = (float*)C + (long)BATCH * OUT_SZ;   // [4096,2048]
#pragma unroll
    for (int n = 0; n < 5; ++n) {
      const int col = ecol + n * 16;
      if (col < OUT_SZ) {
        const float bv = bias0[col];
#pragma unroll
        for (int m = 0; m < 4; ++m) {
          const int row = erow + m * 16;
#pragma unroll
          for (int j = 0; j < 4; ++j)
            outO[(long)(row + j) * OUT_SZ + col] = acc[m][n][j] + bv;
        }
      } else {
        const int hc = col - OUT_SZ;
        const float bv = bias1[hc];
#pragma unroll
        for (int m = 0; m < 4; ++m) {
          const int row = erow + m * 16;
#pragma unroll
          for (int j = 0; j < 4; ++j)
            outH[(long)(row + j) * HID_SZ + hc] = tanhf(acc[m][n][j] + bv);
        }
      }
    }
  }
}

// ---------------- launcher ----------------

extern "C" void kernel_launch(void* const* d_in, const int* in_sizes, int n_in,
                              void* d_out, int out_size, void* d_ws, size_t ws_size,
                              hipStream_t stream) {
  const float* x   = (const float*)d_in[0];
  const float* h   = (const float*)d_in[1];
  const float* Wl  = (const float*)d_in[2];  // [4,2560,2560]
  const float* bl  = (const float*)d_in[3];  // [4,2560]
  const float* Wih = (const float*)d_in[4];  // [2048,2560]
  const float* bih = (const float*)d_in[5];  // [2048]
  const float* Wio = (const float*)d_in[6];  // [512,2560]
  const float* bio = (const float*)d_in[7];  // [512]

  unsigned short* ws   = (unsigned short*)d_ws;
  unsigned short* Wlb  = ws;                                   // 4*2560*2560
  unsigned short* Whb  = Wlb + (long)NLAYER * INNER * INNER;   // fused heads [2560][2560]
  unsigned short* act0 = Whb + (long)INNER * INNER;
  unsigned short* act1 = act0 + (long)BATCH * INNER;

  // fp32 -> bf16 weight conversion (dst contiguous: Wl ++ Wio ++ Wih)
  cvt_all<<<2048, 256, 0, stream>>>(Wl, Wih, Wio, Wlb);
  build_combined<<<2048, 256, 0, stream>>>(x, h, act0);

  // 4 square layers, ping-pong
  unsigned short* a_in = act0;
  unsigned short* a_out = act1;
  for (int l = 0; l < NLAYER; ++l) {
    gemm8<0><<<512, 256, 0, stream>>>(a_in, Wlb + (long)l * INNER * INNER,
                                      bl + (long)l * INNER, nullptr, a_out);
    unsigned short* t = a_in; a_in = a_out; a_out = t;
  }

  // fused heads: output (cols 0-511) + tanh hidden (cols 512-2559)
  gemm8<1><<<512, 256, 0, stream>>>(a_in, Whb, bio, bih, d_out);
}